// Round 1
// baseline (2080.853 us; speedup 1.0000x reference)
//
#include <hip/hip_runtime.h>

#define BB 512
#define NPG 50
#define EPG 60
#define DD 128
#define VV 100000
#define NSPLITS 4
#define FSCALE 12.0f
#define NN (BB*NPG)        // 25600
#define EE (BB*EPG)        // 30720
#define NDTOT (NN*DD)      // 3276800

__device__ __forceinline__ float sigmoidf_(float x){ return 1.f/(1.f+expf(-x)); }

// ---------- stage A: per-row inverse norms of emb ----------
__global__ __launch_bounds__(256) void k_embnorm(const float* __restrict__ emb, float* __restrict__ t_inv) {
  int row = blockIdx.x*4 + (threadIdx.x >> 6);
  int lane = threadIdx.x & 63;
  if (row >= VV) return;
  const float* r = emb + (size_t)row*DD;
  float a = r[lane], b = r[lane+64];
  float s = a*a + b*b;
  for (int off=32; off; off>>=1) s += __shfl_down(s, off);
  if (lane==0) t_inv[row] = 1.0f/fmaxf(sqrtf(s), 1e-12f);
}

// ---------- stage B: feat = emb[iid]*t_inv[iid] ----------
__global__ __launch_bounds__(256) void k_gather(const int* __restrict__ iid, const float* __restrict__ emb,
                                                const float* __restrict__ t_inv, float* __restrict__ feat) {
  int idx = blockIdx.x*256 + threadIdx.x;
  if (idx >= NDTOT) return;
  int n = idx >> 7, d = idx & 127;
  int v = iid[n];
  feat[idx] = emb[(size_t)v*DD + d]*t_inv[v];
}

// ---------- dt = max(edge_t)/SPLITS ----------
__global__ __launch_bounds__(256) void k_dt(const float* __restrict__ edge_t, float* __restrict__ dtp) {
  __shared__ float red[256];
  float m = -1e30f;
  for (int e = threadIdx.x; e < EE; e += 256) m = fmaxf(m, edge_t[e]);
  red[threadIdx.x] = m; __syncthreads();
  for (int s=128; s; s>>=1){ if ((int)threadIdx.x < s) red[threadIdx.x] = fmaxf(red[threadIdx.x], red[threadIdx.x+s]); __syncthreads(); }
  if (threadIdx.x==0) dtp[0] = red[0] / (float)NSPLITS;
}

// ---------- stage C: weighted segment sums ----------
__global__ __launch_bounds__(128) void k_scatter1(const int* __restrict__ src, const int* __restrict__ dst,
                                                  const float* __restrict__ ew, const float* __restrict__ feat,
                                                  float* __restrict__ num1, float* __restrict__ num2,
                                                  float* __restrict__ den1, float* __restrict__ den2) {
  int e = blockIdx.x, d = threadIdx.x;
  int s = src[e], t = dst[e]; float w = ew[e];
  atomicAdd(&num1[(size_t)t*DD+d], feat[(size_t)s*DD+d]*w);
  atomicAdd(&num2[(size_t)s*DD+d], feat[(size_t)t*DD+d]*w);
  if (d==0) { atomicAdd(&den1[t], w); atomicAdd(&den2[s], w); }
}

__global__ __launch_bounds__(256) void k_div(float* __restrict__ num, const float* __restrict__ den) {
  int idx = blockIdx.x*256 + threadIdx.x;
  if (idx >= NDTOT) return;
  float dd = den[idx >> 7];
  num[idx] /= (dd == 0.0f ? 1.0f : dd);
}

// ---------- generic fp32 GEMM: C[M,Nc] = (acc?C:0) + A@B + bias ----------
// B(k,j) = transB ? Bm[j*ldb+k] : Bm[k*ldb+j].  All of M,Nc multiples of 64, K multiple of 16.
__global__ __launch_bounds__(256) void k_sgemm(
    const float* __restrict__ A, int lda,
    const float* __restrict__ Bm, int ldb, int transB,
    const float* __restrict__ bias,
    float* __restrict__ C, int ldc,
    int K, int accumulate)
{
  __shared__ float As[16][68];
  __shared__ float Bs[16][68];
  const int row0 = blockIdx.y*64, col0 = blockIdx.x*64;
  const int tid = threadIdx.x;
  const int tx = tid & 15, ty = tid >> 4;
  float acc[4][4] = {};
  for (int k0 = 0; k0 < K; k0 += 16) {
#pragma unroll
    for (int i = 0; i < 4; ++i) {
      int idx = tid + 256*i;
      int kk = idx & 15, m = idx >> 4;
      As[kk][m] = A[(size_t)(row0+m)*lda + (k0+kk)];
    }
    if (transB) {
#pragma unroll
      for (int i = 0; i < 4; ++i) {
        int idx = tid + 256*i;
        int kk = idx & 15, j = idx >> 4;
        Bs[kk][j] = Bm[(size_t)(col0+j)*ldb + (k0+kk)];
      }
    } else {
#pragma unroll
      for (int i = 0; i < 4; ++i) {
        int idx = tid + 256*i;
        int j = idx & 63, kk = idx >> 6;
        Bs[kk][j] = Bm[(size_t)(k0+kk)*ldb + (col0+j)];
      }
    }
    __syncthreads();
#pragma unroll
    for (int kk = 0; kk < 16; ++kk) {
      float4 a4 = *(const float4*)&As[kk][ty*4];
      float4 b4 = *(const float4*)&Bs[kk][tx*4];
      float av[4] = {a4.x,a4.y,a4.z,a4.w};
      float bv[4] = {b4.x,b4.y,b4.z,b4.w};
#pragma unroll
      for (int i=0;i<4;++i)
#pragma unroll
        for (int j=0;j<4;++j) acc[i][j] += av[i]*bv[j];
    }
    __syncthreads();
  }
#pragma unroll
  for (int i=0;i<4;++i) {
    int r = row0 + ty*4 + i;
#pragma unroll
    for (int j=0;j<4;++j) {
      int c = col0 + tx*4 + j;
      float v = acc[i][j];
      if (bias) v += bias[c];
      size_t off = (size_t)r*ldc + c;
      if (accumulate) v += C[off];
      C[off] = v;
    }
  }
}

// ---------- GRU + l2norm ----------
__global__ __launch_bounds__(128) void k_gru(const float* __restrict__ gi, const float* __restrict__ gh,
                                             const float* __restrict__ feat,
                                             float* __restrict__ x, float* __restrict__ h) {
  int n = blockIdx.x, d = threadIdx.x;
  const float* gin = gi + (size_t)n*384;
  const float* ghn = gh + (size_t)n*384;
  float ir = gin[d], iz = gin[128+d], ig = gin[256+d];
  float hr = ghn[d], hz = ghn[128+d], hg = ghn[256+d];
  float f0 = feat[(size_t)n*DD + d];
  float r = sigmoidf_(ir + hr);
  float z = sigmoidf_(iz + hz);
  float g = tanhf(ig + r*hg);
  float f = (1.f - z)*g + z*f0;
  __shared__ float red2[2];
  float ss = f*f;
  for (int off=32; off; off>>=1) ss += __shfl_down(ss, off);
  if ((d & 63)==0) red2[d>>6] = ss;
  __syncthreads();
  float inv = 1.f/fmaxf(sqrtf(red2[0]+red2[1]), 1e-12f);
  float out = f*inv;
  x[(size_t)n*DD + d] = out;
  h[(size_t)n*DD + d] = out;
}

// ---------- ODE: edge mask + degree ----------
__global__ __launch_bounds__(256) void k_mask(const int* __restrict__ src, const int* __restrict__ dst,
                                              const float* __restrict__ edge_t, const float* __restrict__ node_t,
                                              const float* __restrict__ dtp, int kstep,
                                              float* __restrict__ emf, float* __restrict__ deg) {
  int e = blockIdx.x*256 + threadIdx.x;
  if (e >= EE) return;
  float t = (float)kstep * dtp[0];
  int s = src[e], d = dst[e];
  float m = (edge_t[e] <= t && node_t[s] >= t && node_t[d] >= t && s != d) ? 1.0f : 0.0f;
  emf[e] = m;
  if (m != 0.0f) { atomicAdd(&deg[s], 1.0f); atomicAdd(&deg[d], 1.0f); }
}

__global__ __launch_bounds__(256) void k_dis(const float* __restrict__ deg, float* __restrict__ dis) {
  int n = blockIdx.x*256 + threadIdx.x;
  if (n >= NN) return;
  dis[n] = 1.0f/sqrtf(fmaxf(deg[n], 1.0f));
}

__global__ __launch_bounds__(128) void k_scatter_xh(const int* __restrict__ src, const int* __restrict__ dst,
                                                    const float* __restrict__ emf, const float* __restrict__ dis,
                                                    const float* __restrict__ x, const float* __restrict__ h,
                                                    float* __restrict__ aggx, float* __restrict__ aggh) {
  int e = blockIdx.x;
  if (emf[e] == 0.0f) return;
  int d = threadIdx.x;
  int s = src[e], t = dst[e];
  float ds = dis[s], dt_ = dis[t];
  atomicAdd(&aggx[(size_t)t*DD+d], x[(size_t)s*DD+d]*ds);
  atomicAdd(&aggx[(size_t)s*DD+d], x[(size_t)t*DD+d]*dt_);
  atomicAdd(&aggh[(size_t)t*DD+d], h[(size_t)s*DD+d]*ds);
  atomicAdd(&aggh[(size_t)s*DD+d], h[(size_t)t*DD+d]*dt_);
}

__global__ __launch_bounds__(128) void k_scatter_rh(const int* __restrict__ src, const int* __restrict__ dst,
                                                    const float* __restrict__ emf, const float* __restrict__ dis,
                                                    const float* __restrict__ rh, float* __restrict__ agg) {
  int e = blockIdx.x;
  if (emf[e] == 0.0f) return;
  int d = threadIdx.x;
  int s = src[e], t = dst[e];
  atomicAdd(&agg[(size_t)t*DD+d], rh[(size_t)s*DD+d]*dis[s]);
  atomicAdd(&agg[(size_t)s*DD+d], rh[(size_t)t*DD+d]*dis[t]);
}

__global__ __launch_bounds__(256) void k_scalerows(float* __restrict__ buf, const float* __restrict__ dis, int total) {
  int idx = blockIdx.x*256 + threadIdx.x;
  if (idx >= total) return;
  int n = (idx >> 7) % NN;
  buf[idx] *= dis[n];
}

__global__ __launch_bounds__(256) void k_rz(const float* __restrict__ Cr, float* __restrict__ Cz,
                                            const float* __restrict__ h, float* __restrict__ rh) {
  int idx = blockIdx.x*256 + threadIdx.x;
  if (idx >= NDTOT) return;
  float r = sigmoidf_(Cr[idx]);
  Cz[idx] = sigmoidf_(Cz[idx]);
  rh[idx] = r*h[idx];
}

__global__ __launch_bounds__(256) void k_update(const float* __restrict__ Cu, const float* __restrict__ Cz,
                                                float* __restrict__ h, const float* __restrict__ node_t,
                                                const float* __restrict__ dtp, int kstep) {
  int idx = blockIdx.x*256 + threadIdx.x;
  if (idx >= NDTOT) return;
  int n = idx >> 7;
  float dt = dtp[0];
  float t = (float)kstep * dt;
  if (node_t[n] >= t) {
    float uu = tanhf(Cu[idx]);
    float dh = (1.f - Cz[idx])*(uu - h[idx]);
    h[idx] += dt*dh;
  }
}

// ---------- row l2norm (h -> fb) ----------
__global__ __launch_bounds__(128) void k_l2rows(const float* __restrict__ in, float* __restrict__ out) {
  int n = blockIdx.x, d = threadIdx.x;
  float v = in[(size_t)n*DD + d];
  __shared__ float red2[2];
  float ss = v*v;
  for (int off=32; off; off>>=1) ss += __shfl_down(ss, off);
  if ((d & 63)==0) red2[d>>6] = ss;
  __syncthreads();
  float inv = 1.f/fmaxf(sqrtf(red2[0]+red2[1]), 1e-12f);
  out[(size_t)n*DD + d] = v*inv;
}

// ---------- attention readout + W_sr + l2norm -> sr (B x D) ----------
__global__ __launch_bounds__(128) void k_attn(const float* __restrict__ fb, const float* __restrict__ U,
                                              const float* __restrict__ lv, const float* __restrict__ We,
                                              const float* __restrict__ W_sr, float* __restrict__ sr) {
  int b = blockIdx.x, d = threadIdx.x;
  __shared__ float sc[NPG];
  __shared__ float lastv[DD], srg[DD];
  __shared__ float red2[2];
  const float* Ub  = U  + (size_t)b*NPG*DD;
  const float* lvb = lv + (size_t)b*DD;
  if (d < 64) {
    for (int i=0;i<NPG;++i) {
      float e = We[d]   * sigmoidf_(Ub[i*DD + d]      + lvb[d]) +
                We[d+64]* sigmoidf_(Ub[i*DD + 64 + d] + lvb[d+64]);
      for (int off=32; off; off>>=1) e += __shfl_down(e, off);
      if (d==0) sc[i] = e;
    }
  }
  __syncthreads();
  if (d < 64) {
    float v = (d < NPG) ? sc[d] : -1e30f;
    float m = v;
    for (int off=1; off<64; off<<=1) m = fmaxf(m, __shfl_xor(m, off));
    float ex = (d < NPG) ? expf(v - m) : 0.f;
    float s = ex;
    for (int off=1; off<64; off<<=1) s += __shfl_xor(s, off);
    if (d < NPG) sc[d] = ex/s;
  }
  __syncthreads();
  const float* fbb = fb + (size_t)b*NPG*DD;
  float lastd = fbb[(NPG-1)*DD + d];
  float sg = 0.f;
  for (int i=0;i<NPG;++i) sg += fbb[i*DD + d]*sc[i];
  lastv[d] = lastd; srg[d] = sg;
  __syncthreads();
  float acc = 0.f;
  for (int k=0;k<DD;++k) acc += lastv[k]*W_sr[k*DD + d];
  for (int k=0;k<DD;++k) acc += srg[k]*W_sr[(DD+k)*DD + d];
  float ss = acc*acc;
  for (int off=32; off; off>>=1) ss += __shfl_down(ss, off);
  if ((d & 63)==0) red2[d>>6] = ss;
  __syncthreads();
  float inv = 1.f/fmaxf(sqrtf(red2[0]+red2[1]), 1e-12f);
  sr[(size_t)b*DD + d] = acc*inv;
}

// ---------- logits = SCALE * sr @ (emb*t_inv).T ----------
__global__ __launch_bounds__(256) void k_logits(const float* __restrict__ srv, const float* __restrict__ emb,
                                                const float* __restrict__ t_inv, float* __restrict__ out) {
  __shared__ float As[16][68];
  __shared__ float Bs[16][68];
  const int col0 = blockIdx.x*64, row0 = blockIdx.y*64;
  const int tid = threadIdx.x;
  const int tx = tid & 15, ty = tid >> 4;
  float acc[4][4] = {};
  for (int k0 = 0; k0 < 128; k0 += 16) {
#pragma unroll
    for (int i = 0; i < 4; ++i) {
      int idx = tid + 256*i;
      int kk = idx & 15, m = idx >> 4;
      As[kk][m] = srv[(size_t)(row0+m)*DD + (k0+kk)];
    }
#pragma unroll
    for (int i = 0; i < 4; ++i) {
      int idx = tid + 256*i;
      int kk = idx & 15, j = idx >> 4;
      int v = col0 + j;
      Bs[kk][j] = (v < VV) ? emb[(size_t)v*DD + (k0+kk)] : 0.f;
    }
    __syncthreads();
#pragma unroll
    for (int kk = 0; kk < 16; ++kk) {
      float4 a4 = *(const float4*)&As[kk][ty*4];
      float4 b4 = *(const float4*)&Bs[kk][tx*4];
      float av[4] = {a4.x,a4.y,a4.z,a4.w};
      float bv[4] = {b4.x,b4.y,b4.z,b4.w};
#pragma unroll
      for (int i=0;i<4;++i)
#pragma unroll
        for (int j=0;j<4;++j) acc[i][j] += av[i]*bv[j];
    }
    __syncthreads();
  }
#pragma unroll
  for (int i=0;i<4;++i) {
    int r = row0 + ty*4 + i;
#pragma unroll
    for (int j=0;j<4;++j) {
      int c = col0 + tx*4 + j;
      if (c < VV) out[(size_t)r*VV + c] = FSCALE*acc[i][j]*t_inv[c];
    }
  }
}

// ---------- per-row logsumexp ----------
__global__ __launch_bounds__(256) void k_rowlse(const float* __restrict__ out, float* __restrict__ lse) {
  int b = blockIdx.x, tid = threadIdx.x;
  const float* row = out + (size_t)b*VV;
  float m = -1e30f, s = 0.f;
  for (int v = tid; v < VV; v += 256) {
    float x = row[v];
    if (x > m) { s = s*expf(m - x) + 1.f; m = x; }
    else s += expf(x - m);
  }
  __shared__ float ms[256], ssh[256];
  ms[tid] = m; ssh[tid] = s; __syncthreads();
  for (int st=128; st; st>>=1) {
    if (tid < st) {
      float m2 = ms[tid+st], s2 = ssh[tid+st];
      float M = fmaxf(ms[tid], m2);
      ssh[tid] = ssh[tid]*expf(ms[tid]-M) + s2*expf(m2-M);
      ms[tid] = M;
    }
    __syncthreads();
  }
  if (tid==0) lse[b] = ms[0] + logf(ssh[0]);
}

__global__ __launch_bounds__(256) void k_sub(float* __restrict__ out, const float* __restrict__ lse) {
  int idx = blockIdx.x*256 + threadIdx.x;
  int base = idx*4;
  if (base >= BB*VV) return;
  float l = lse[base / VV];
  float4* p = (float4*)(out + base);
  float4 v = *p;
  v.x -= l; v.y -= l; v.z -= l; v.w -= l;
  *p = v;
}

extern "C" void kernel_launch(void* const* d_in, const int* in_sizes, int n_in,
                              void* d_out, int out_size, void* d_ws, size_t ws_size,
                              hipStream_t stream) {
  (void)in_sizes; (void)n_in; (void)out_size; (void)ws_size;
  const int*   iid    = (const int*)  d_in[0];
  const int*   src    = (const int*)  d_in[1];
  const int*   dst    = (const int*)  d_in[2];
  const float* edge_w = (const float*)d_in[3];
  const float* edge_t = (const float*)d_in[4];
  const float* node_t = (const float*)d_in[5];
  const float* emb    = (const float*)d_in[6];
  const float* W1     = (const float*)d_in[7];
  const float* W2     = (const float*)d_in[8];
  const float* gw_ih  = (const float*)d_in[9];
  const float* gw_hh  = (const float*)d_in[10];
  const float* gb_ih  = (const float*)d_in[11];
  const float* gb_hh  = (const float*)d_in[12];
  const float* Wxr = (const float*)d_in[13]; const float* bxr = (const float*)d_in[14];
  const float* Wxz = (const float*)d_in[15]; const float* bxz = (const float*)d_in[16];
  const float* Wxh = (const float*)d_in[17]; const float* bxh = (const float*)d_in[18];
  const float* Whr = (const float*)d_in[19]; const float* bhr = (const float*)d_in[20];
  const float* Whz = (const float*)d_in[21]; const float* bhz = (const float*)d_in[22];
  const float* Whh = (const float*)d_in[23]; const float* bhh = (const float*)d_in[24];
  const float* Wu  = (const float*)d_in[25];
  const float* Wv  = (const float*)d_in[26]; const float* bv  = (const float*)d_in[27];
  const float* We  = (const float*)d_in[28];
  const float* W_sr= (const float*)d_in[29];

  float* ws  = (float*)d_ws;
  float* out = (float*)d_out;

  // workspace layout (floats)
  float* t_inv = ws;                 // VV
  float* x     = t_inv + VV;         // NDTOT (feat -> x -> fb)
  float* h     = x + NDTOT;          // NDTOT
  float* den1  = h + NDTOT;          // NN
  float* den2  = den1 + NN;          // NN
  float* deg   = den2 + NN;          // NN
  float* dis   = deg + NN;           // NN
  float* emf   = dis + NN;           // EE
  float* M1    = emf + EE;           // 128*384
  float* M2    = M1 + 128*384;       // 128*384
  float* lv    = M2 + 128*384;       // BB*DD
  float* srv   = lv + (size_t)BB*DD; // BB*DD
  float* dtp   = srv + (size_t)BB*DD;// 1
  float* lse   = dtp + 1;            // BB

  // d_out used as scratch until the final logits pass (51.2M floats available)
  float* gi   = out;                          // NN*384 = 3*NDTOT
  float* gh   = out + (size_t)3*NDTOT;        // NN*384
  float* num1 = out + (size_t)6*NDTOT;        // NDTOT
  float* num2 = out + (size_t)7*NDTOT;        // NDTOT
  float* aggx  = out;                         // ODE phase
  float* aggh  = out + (size_t)NDTOT;
  float* aggrh = out + (size_t)2*NDTOT;
  float* Cr    = out + (size_t)3*NDTOT;
  float* Cz    = out + (size_t)4*NDTOT;
  float* Cu    = out + (size_t)5*NDTOT;
  float* rh    = out + (size_t)6*NDTOT;
  float* U     = out;                         // attention phase

  // ---- stage A/B ----
  k_embnorm<<<VV/4, 256, 0, stream>>>(emb, t_inv);
  k_gather<<<NDTOT/256, 256, 0, stream>>>(iid, emb, t_inv, x);
  k_dt<<<1, 256, 0, stream>>>(edge_t, dtp);

  // ---- stage C: neighbor means ----
  hipMemsetAsync(num1, 0, (size_t)2*NDTOT*sizeof(float), stream);
  hipMemsetAsync(den1, 0, (size_t)2*NN*sizeof(float), stream);
  k_scatter1<<<EE, 128, 0, stream>>>(src, dst, edge_w, x, num1, num2, den1, den2);
  k_div<<<NDTOT/256, 256, 0, stream>>>(num1, den1);
  k_div<<<NDTOT/256, 256, 0, stream>>>(num2, den2);

  // ---- stage D: GRU ----
  dim3 gM(384/64, 128/64);
  k_sgemm<<<gM, 256, 0, stream>>>(W1, 128, gw_ih,     256, 1, nullptr, M1, 384, 128, 0);
  k_sgemm<<<gM, 256, 0, stream>>>(W2, 128, gw_ih+128, 256, 1, nullptr, M2, 384, 128, 0);
  dim3 gN384(384/64, NN/64);
  k_sgemm<<<gN384, 256, 0, stream>>>(num1, 128, M1, 384, 0, gb_ih,  gi, 384, 128, 0);
  k_sgemm<<<gN384, 256, 0, stream>>>(num2, 128, M2, 384, 0, nullptr, gi, 384, 128, 1);
  k_sgemm<<<gN384, 256, 0, stream>>>(x,    128, gw_hh, 128, 1, gb_hh, gh, 384, 128, 0);
  k_gru<<<NN, 128, 0, stream>>>(gi, gh, x, x, h);

  // ---- stage E: ODE, 4 Euler steps ----
  dim3 gN128(128/64, NN/64);
  for (int k = 0; k < NSPLITS; ++k) {
    hipMemsetAsync(deg, 0, (size_t)NN*sizeof(float), stream);
    k_mask<<<EE/256, 256, 0, stream>>>(src, dst, edge_t, node_t, dtp, k, emf, deg);
    k_dis<<<(NN+255)/256, 256, 0, stream>>>(deg, dis);
    hipMemsetAsync(aggx, 0, (size_t)2*NDTOT*sizeof(float), stream);
    k_scatter_xh<<<EE, 128, 0, stream>>>(src, dst, emf, dis, x, h, aggx, aggh);
    k_scalerows<<<(2*NDTOT)/256, 256, 0, stream>>>(aggx, dis, 2*NDTOT);
    k_sgemm<<<gN128, 256, 0, stream>>>(aggx, 128, Wxr, 128, 0, bxr, Cr, 128, 128, 0);
    k_sgemm<<<gN128, 256, 0, stream>>>(aggh, 128, Whr, 128, 0, bhr, Cr, 128, 128, 1);
    k_sgemm<<<gN128, 256, 0, stream>>>(aggx, 128, Wxz, 128, 0, bxz, Cz, 128, 128, 0);
    k_sgemm<<<gN128, 256, 0, stream>>>(aggh, 128, Whz, 128, 0, bhz, Cz, 128, 128, 1);
    k_rz<<<NDTOT/256, 256, 0, stream>>>(Cr, Cz, h, rh);
    hipMemsetAsync(aggrh, 0, (size_t)NDTOT*sizeof(float), stream);
    k_scatter_rh<<<EE, 128, 0, stream>>>(src, dst, emf, dis, rh, aggrh);
    k_scalerows<<<NDTOT/256, 256, 0, stream>>>(aggrh, dis, NDTOT);
    k_sgemm<<<gN128, 256, 0, stream>>>(aggx,  128, Wxh, 128, 0, bxh, Cu, 128, 128, 0);
    k_sgemm<<<gN128, 256, 0, stream>>>(aggrh, 128, Whh, 128, 0, bhh, Cu, 128, 128, 1);
    k_update<<<NDTOT/256, 256, 0, stream>>>(Cu, Cz, h, node_t, dtp, k);
  }

  // ---- stage F: attention readout ----
  k_l2rows<<<NN, 128, 0, stream>>>(h, x);          // fb into x
  k_sgemm<<<gN128, 256, 0, stream>>>(x, 128, Wu, 128, 0, nullptr, U, 128, 128, 0);
  dim3 gB(128/64, BB/64);
  k_sgemm<<<gB, 256, 0, stream>>>(x + (size_t)(NPG-1)*DD, NPG*DD, Wv, 128, 0, bv, lv, 128, 128, 0);
  k_attn<<<BB, 128, 0, stream>>>(x, U, lv, We, W_sr, srv);

  // ---- stage G: logits + log_softmax ----
  dim3 gL((VV+63)/64, BB/64);
  k_logits<<<gL, 256, 0, stream>>>(srv, emb, t_inv, out);
  k_rowlse<<<BB, 256, 0, stream>>>(out, lse);
  k_sub<<<((BB*VV/4)+255)/256, 256, 0, stream>>>(out, lse);
}

// Round 2
// 1436.445 us; speedup vs baseline: 1.4486x; 1.4486x over previous
//
#include <hip/hip_runtime.h>

#define BB 512
#define NPG 50
#define EPG 60
#define DD 128
#define VV 100000
#define NSPLITS 4
#define FSCALE 12.0f
#define NN (BB*NPG)        // 25600
#define EE (BB*EPG)        // 30720
#define NDTOT (NN*DD)      // 3276800
#define NCB ((VV+127)/128) // 782

__device__ __forceinline__ float sigmoidf_(float x){ return 1.f/(1.f+expf(-x)); }

// ---------- per-row inverse norms of emb ----------
__global__ __launch_bounds__(256) void k_embnorm(const float* __restrict__ emb, float* __restrict__ t_inv) {
  int row = blockIdx.x*4 + (threadIdx.x >> 6);
  int lane = threadIdx.x & 63;
  if (row >= VV) return;
  const float* r = emb + (size_t)row*DD;
  float a = r[lane], b = r[lane+64];
  float s = a*a + b*b;
  for (int off=32; off; off>>=1) s += __shfl_down(s, off);
  if (lane==0) t_inv[row] = 1.0f/fmaxf(sqrtf(s), 1e-12f);
}

// ---------- feat = emb[iid]*t_inv[iid] ----------
__global__ __launch_bounds__(256) void k_gather(const int* __restrict__ iid, const float* __restrict__ emb,
                                                const float* __restrict__ t_inv, float* __restrict__ feat) {
  int idx = blockIdx.x*256 + threadIdx.x;
  if (idx >= NDTOT) return;
  int n = idx >> 7, d = idx & 127;
  int v = iid[n];
  feat[idx] = emb[(size_t)v*DD + d]*t_inv[v];
}

// ---------- dt = max(edge_t)/SPLITS ----------
__global__ __launch_bounds__(256) void k_dt(const float* __restrict__ edge_t, float* __restrict__ dtp) {
  __shared__ float red[256];
  float m = -1e30f;
  for (int e = threadIdx.x; e < EE; e += 256) m = fmaxf(m, edge_t[e]);
  red[threadIdx.x] = m; __syncthreads();
  for (int s=128; s; s>>=1){ if ((int)threadIdx.x < s) red[threadIdx.x] = fmaxf(red[threadIdx.x], red[threadIdx.x+s]); __syncthreads(); }
  if (threadIdx.x==0) dtp[0] = red[0] / (float)NSPLITS;
}

// ---------- weight prep ----------
__global__ void k_transpose(const float* __restrict__ src, float* __restrict__ dst, int cols) {
  int r = blockIdx.x, c = threadIdx.x;
  dst[(size_t)c*gridDim.x + r] = src[(size_t)r*cols + c];
}
__global__ void k_build_wrz(const float* __restrict__ Wxr, const float* __restrict__ Wxz,
                            const float* __restrict__ Whr, const float* __restrict__ Whz,
                            float* __restrict__ Wrz) {
  int k = blockIdx.x, c = threadIdx.x;
  float v;
  if (k < 128) v = (c < 128) ? Wxr[k*128+c] : Wxz[k*128+(c-128)];
  else         v = (c < 128) ? Whr[(k-128)*128+c] : Whz[(k-128)*128+(c-128)];
  Wrz[k*256+c] = v;
}
__global__ void k_build_wu(const float* __restrict__ Wxh, const float* __restrict__ Whh, float* __restrict__ Wu2) {
  int k = blockIdx.x, c = threadIdx.x;
  Wu2[k*128+c] = (k < 128) ? Wxh[k*128+c] : Whh[(k-128)*128+c];
}
__global__ void k_build_bias(const float* __restrict__ bxr, const float* __restrict__ bhr,
                             const float* __restrict__ bxz, const float* __restrict__ bhz,
                             const float* __restrict__ bxh, const float* __restrict__ bhh,
                             float* __restrict__ brz, float* __restrict__ bu) {
  int t = threadIdx.x;
  if (t < 128) brz[t] = bxr[t] + bhr[t];
  else if (t < 256) brz[t] = bxz[t-128] + bhz[t-128];
  else bu[t-256] = bxh[t-256] + bhh[t-256];
}

// ---------- per-group stage-C means: neigh1 -> AB[:,0:128], neigh2 -> AB[:,128:256] ----------
__global__ __launch_bounds__(128) void k_grp_mean1(const int* __restrict__ src, const int* __restrict__ dst,
                                                   const float* __restrict__ ew, const float* __restrict__ feat,
                                                   float* __restrict__ AB) {
  __shared__ float fl[NPG*128];
  __shared__ float n1[NPG*128];
  __shared__ int sl[EPG], tl[EPG];
  __shared__ float wl[EPG];
  __shared__ float d1[NPG];
  int b = blockIdx.x, d = threadIdx.x;
  int nb = b*NPG, eb = b*EPG;
  for (int i = d; i < NPG*32; i += 128) {
    ((float4*)fl)[i] = ((const float4*)(feat + (size_t)nb*128))[i];
    ((float4*)n1)[i] = make_float4(0.f,0.f,0.f,0.f);
  }
  if (d < EPG) { sl[d] = src[eb+d]-nb; tl[d] = dst[eb+d]-nb; wl[d] = ew[eb+d]; }
  __syncthreads();
  for (int e = 0; e < EPG; ++e)
    n1[tl[e]*128+d] += fl[sl[e]*128+d]*wl[e];
  if (d < NPG) {
    float den = 0.f;
    for (int e = 0; e < EPG; ++e) den += (tl[e]==d) ? wl[e] : 0.f;
    d1[d] = (den == 0.f) ? 1.f : den;
  }
  __syncthreads();
  for (int n = 0; n < NPG; ++n)
    AB[(size_t)(nb+n)*256 + d] = n1[n*128+d]/d1[n];
}
__global__ __launch_bounds__(128) void k_grp_mean2(const int* __restrict__ src, const int* __restrict__ dst,
                                                   const float* __restrict__ ew, const float* __restrict__ feat,
                                                   float* __restrict__ AB) {
  __shared__ float fl[NPG*128];
  __shared__ float n2[NPG*128];
  __shared__ int sl[EPG], tl[EPG];
  __shared__ float wl[EPG];
  __shared__ float d2[NPG];
  int b = blockIdx.x, d = threadIdx.x;
  int nb = b*NPG, eb = b*EPG;
  for (int i = d; i < NPG*32; i += 128) {
    ((float4*)fl)[i] = ((const float4*)(feat + (size_t)nb*128))[i];
    ((float4*)n2)[i] = make_float4(0.f,0.f,0.f,0.f);
  }
  if (d < EPG) { sl[d] = src[eb+d]-nb; tl[d] = dst[eb+d]-nb; wl[d] = ew[eb+d]; }
  __syncthreads();
  for (int e = 0; e < EPG; ++e)
    n2[sl[e]*128+d] += fl[tl[e]*128+d]*wl[e];
  if (d < NPG) {
    float den = 0.f;
    for (int e = 0; e < EPG; ++e) den += (sl[e]==d) ? wl[e] : 0.f;
    d2[d] = (den == 0.f) ? 1.f : den;
  }
  __syncthreads();
  for (int n = 0; n < NPG; ++n)
    AB[(size_t)(nb+n)*256 + 128 + d] = n2[n*128+d]/d2[n];
}

// ---------- GRU + l2norm ----------
__global__ __launch_bounds__(128) void k_gru(const float* __restrict__ gi, const float* __restrict__ gh,
                                             float* __restrict__ x, float* __restrict__ h) {
  int n = blockIdx.x, d = threadIdx.x;
  const float* gin = gi + (size_t)n*384;
  const float* ghn = gh + (size_t)n*384;
  float ir = gin[d], iz = gin[128+d], ig = gin[256+d];
  float hr = ghn[d], hz = ghn[128+d], hg = ghn[256+d];
  float f0 = x[(size_t)n*DD + d];
  float r = sigmoidf_(ir + hr);
  float z = sigmoidf_(iz + hz);
  float g = tanhf(ig + r*hg);
  float f = (1.f - z)*g + z*f0;
  __shared__ float red2[2];
  float ss = f*f;
  for (int off=32; off; off>>=1) ss += __shfl_down(ss, off);
  if ((d & 63)==0) red2[d>>6] = ss;
  __syncthreads();
  float inv = 1.f/fmaxf(sqrtf(red2[0]+red2[1]), 1e-12f);
  float out = f*inv;
  x[(size_t)n*DD + d] = out;
  h[(size_t)n*DD + d] = out;
}

// ---------- ODE per-group aggregation: mask/deg/dis + aggx (scaled) ----------
__global__ __launch_bounds__(128) void k_ode_agg1x(const int* __restrict__ src, const int* __restrict__ dst,
                                                   const float* __restrict__ edge_t, const float* __restrict__ node_t,
                                                   const float* __restrict__ dtp, int kstep,
                                                   const float* __restrict__ x, float* __restrict__ AB,
                                                   float* __restrict__ dis_ws, float* __restrict__ emf_ws) {
  __shared__ float xl[NPG*128];
  __shared__ float ax[NPG*128];
  __shared__ int sl[EPG], tl[EPG];
  __shared__ float actl[EPG];
  __shared__ float disl[NPG];
  __shared__ float ntl[NPG];
  int b = blockIdx.x, d = threadIdx.x;
  int nb = b*NPG, eb = b*EPG;
  float t = (float)kstep * dtp[0];
  if (d < EPG) { sl[d] = src[eb+d]-nb; tl[d] = dst[eb+d]-nb; }
  if (d < NPG) ntl[d] = node_t[nb+d];
  for (int i = d; i < NPG*32; i += 128) {
    ((float4*)xl)[i] = ((const float4*)(x + (size_t)nb*128))[i];
    ((float4*)ax)[i] = make_float4(0.f,0.f,0.f,0.f);
  }
  __syncthreads();
  if (d < EPG) {
    int s = sl[d], tt = tl[d];
    actl[d] = (edge_t[eb+d] <= t && ntl[s] >= t && ntl[tt] >= t && s != tt) ? 1.f : 0.f;
    emf_ws[eb+d] = 0.f;  // placeholder, overwritten after sync with final value
  }
  __syncthreads();
  if (d < NPG) {
    float deg = 0.f;
    for (int e = 0; e < EPG; ++e) deg += actl[e]*((sl[e]==d ? 1.f:0.f)+(tl[e]==d ? 1.f:0.f));
    disl[d] = rsqrtf(fmaxf(deg, 1.f));
    dis_ws[nb+d] = disl[d];
  }
  if (d < EPG) emf_ws[eb+d] = actl[d];
  __syncthreads();
  for (int e = 0; e < EPG; ++e) {
    if (actl[e] != 0.f) {
      int s = sl[e], tt = tl[e];
      ax[tt*128+d] += xl[s*128+d]*disl[s];
      ax[s*128+d]  += xl[tt*128+d]*disl[tt];
    }
  }
  __syncthreads();
  for (int n = 0; n < NPG; ++n)
    AB[(size_t)(nb+n)*256 + d] = ax[n*128+d]*disl[n];
}

// aggh (scaled) -> AB[:,128:256], using saved mask/dis
__global__ __launch_bounds__(128) void k_ode_agg1h(const int* __restrict__ src, const int* __restrict__ dst,
                                                   const float* __restrict__ emf_ws, const float* __restrict__ dis_ws,
                                                   const float* __restrict__ h, float* __restrict__ AB) {
  __shared__ float hl[NPG*128];
  __shared__ float ah[NPG*128];
  __shared__ int sl[EPG], tl[EPG];
  __shared__ float actl[EPG];
  __shared__ float disl[NPG];
  int b = blockIdx.x, d = threadIdx.x;
  int nb = b*NPG, eb = b*EPG;
  if (d < EPG) { sl[d] = src[eb+d]-nb; tl[d] = dst[eb+d]-nb; actl[d] = emf_ws[eb+d]; }
  if (d < NPG) disl[d] = dis_ws[nb+d];
  for (int i = d; i < NPG*32; i += 128) {
    ((float4*)hl)[i] = ((const float4*)(h + (size_t)nb*128))[i];
    ((float4*)ah)[i] = make_float4(0.f,0.f,0.f,0.f);
  }
  __syncthreads();
  for (int e = 0; e < EPG; ++e) {
    if (actl[e] != 0.f) {
      int s = sl[e], tt = tl[e];
      ah[tt*128+d] += hl[s*128+d]*disl[s];
      ah[s*128+d]  += hl[tt*128+d]*disl[tt];
    }
  }
  __syncthreads();
  for (int n = 0; n < NPG; ++n)
    AB[(size_t)(nb+n)*256 + 128 + d] = ah[n*128+d]*disl[n];
}

// agg(rh) (scaled) -> AB[:,128:256]; rh read from Crz[:,0:128]
__global__ __launch_bounds__(128) void k_ode_agg2(const int* __restrict__ src, const int* __restrict__ dst,
                                                  const float* __restrict__ emf_ws, const float* __restrict__ dis_ws,
                                                  const float* __restrict__ Crz, float* __restrict__ AB) {
  __shared__ float rl[NPG*128];
  __shared__ float ar[NPG*128];
  __shared__ int sl[EPG], tl[EPG];
  __shared__ float actl[EPG];
  __shared__ float disl[NPG];
  int b = blockIdx.x, d = threadIdx.x;
  int nb = b*NPG, eb = b*EPG;
  if (d < EPG) { sl[d] = src[eb+d]-nb; tl[d] = dst[eb+d]-nb; actl[d] = emf_ws[eb+d]; }
  if (d < NPG) disl[d] = dis_ws[nb+d];
  for (int i = d; i < NPG*32; i += 128) {
    int n = i >> 5, q = i & 31;
    ((float4*)rl)[i] = *(const float4*)&Crz[(size_t)(nb+n)*256 + q*4];
    ((float4*)ar)[i] = make_float4(0.f,0.f,0.f,0.f);
  }
  __syncthreads();
  for (int e = 0; e < EPG; ++e) {
    if (actl[e] != 0.f) {
      int s = sl[e], tt = tl[e];
      ar[tt*128+d] += rl[s*128+d]*disl[s];
      ar[s*128+d]  += rl[tt*128+d]*disl[tt];
    }
  }
  __syncthreads();
  for (int n = 0; n < NPG; ++n)
    AB[(size_t)(nb+n)*256 + 128 + d] = ar[n*128+d]*disl[n];
}

// ---------- 128x128-tile fp32 GEMM, 8x8 per thread, fused epilogues ----------
// mode 0: C = A@B + bias
// mode 2: Crz epilogue: s=sigmoid(acc+bias[c]); c<128 -> s*hin ; else s      (ldc=256)
// mode 3: uu=tanh(acc+bias[c]); h += dtp*(1-z)*(uu-h) where node alive       (N=128)
__global__ __launch_bounds__(256) void gemm128(
    const float* __restrict__ A, int lda,
    const float* __restrict__ B, int ldb,
    const float* __restrict__ bias,
    float* __restrict__ C, int ldc,
    int K, int mode,
    const float* __restrict__ hin,
    float* __restrict__ hio,
    const float* __restrict__ zbuf,
    const float* __restrict__ node_t,
    const float* __restrict__ dtp, int kstep)
{
  __shared__ float As[16][132];
  __shared__ float Bs[16][132];
  const int row0 = blockIdx.y*128, col0 = blockIdx.x*128;
  const int tid = threadIdx.x;
  const int tx = tid & 15, ty = tid >> 4;
  float acc[8][8] = {};
  for (int k0 = 0; k0 < K; k0 += 16) {
#pragma unroll
    for (int i = 0; i < 2; ++i) {
      int idx = tid + 256*i;
      int m = idx >> 2, kq = idx & 3;
      float4 v = *(const float4*)&A[(size_t)(row0+m)*lda + k0 + kq*4];
      As[kq*4+0][m] = v.x; As[kq*4+1][m] = v.y; As[kq*4+2][m] = v.z; As[kq*4+3][m] = v.w;
    }
#pragma unroll
    for (int i = 0; i < 2; ++i) {
      int idx = tid + 256*i;
      int kk = idx >> 5, jq = idx & 31;
      float4 v = *(const float4*)&B[(size_t)(k0+kk)*ldb + col0 + jq*4];
      *(float4*)&Bs[kk][jq*4] = v;
    }
    __syncthreads();
#pragma unroll
    for (int kk = 0; kk < 16; ++kk) {
      float4 a0 = *(const float4*)&As[kk][ty*8];
      float4 a1 = *(const float4*)&As[kk][ty*8+4];
      float4 b0 = *(const float4*)&Bs[kk][tx*8];
      float4 b1 = *(const float4*)&Bs[kk][tx*8+4];
      float av[8] = {a0.x,a0.y,a0.z,a0.w,a1.x,a1.y,a1.z,a1.w};
      float bv[8] = {b0.x,b0.y,b0.z,b0.w,b1.x,b1.y,b1.z,b1.w};
#pragma unroll
      for (int i=0;i<8;++i)
#pragma unroll
        for (int j=0;j<8;++j) acc[i][j] += av[i]*bv[j];
    }
    __syncthreads();
  }
  const int cbase = col0 + tx*8;
  if (mode == 0) {
    float bb[8];
#pragma unroll
    for (int j=0;j<8;++j) bb[j] = bias ? bias[cbase+j] : 0.f;
#pragma unroll
    for (int i=0;i<8;++i) {
      int r = row0 + ty*8 + i;
      float4 o0 = make_float4(acc[i][0]+bb[0], acc[i][1]+bb[1], acc[i][2]+bb[2], acc[i][3]+bb[3]);
      float4 o1 = make_float4(acc[i][4]+bb[4], acc[i][5]+bb[5], acc[i][6]+bb[6], acc[i][7]+bb[7]);
      *(float4*)&C[(size_t)r*ldc + cbase] = o0;
      *(float4*)&C[(size_t)r*ldc + cbase + 4] = o1;
    }
  } else if (mode == 2) {
    float bb[8];
#pragma unroll
    for (int j=0;j<8;++j) bb[j] = bias[cbase+j];
    const bool is_r = (col0 == 0);
#pragma unroll
    for (int i=0;i<8;++i) {
      int r = row0 + ty*8 + i;
      float o[8];
#pragma unroll
      for (int j=0;j<8;++j) {
        float s = sigmoidf_(acc[i][j] + bb[j]);
        o[j] = is_r ? s*hin[(size_t)r*128 + cbase + j] : s;
      }
      *(float4*)&C[(size_t)r*256 + cbase] = make_float4(o[0],o[1],o[2],o[3]);
      *(float4*)&C[(size_t)r*256 + cbase + 4] = make_float4(o[4],o[5],o[6],o[7]);
    }
  } else { // mode 3
    float bb[8];
#pragma unroll
    for (int j=0;j<8;++j) bb[j] = bias[cbase+j];
    float dtv = dtp[0];
    float tt = (float)kstep * dtv;
#pragma unroll
    for (int i=0;i<8;++i) {
      int r = row0 + ty*8 + i;
      if (node_t[r] >= tt) {
        float4 h0 = *(const float4*)&hio[(size_t)r*128 + cbase];
        float4 h1 = *(const float4*)&hio[(size_t)r*128 + cbase + 4];
        float4 z0 = *(const float4*)&zbuf[(size_t)r*256 + 128 + cbase];
        float4 z1 = *(const float4*)&zbuf[(size_t)r*256 + 128 + cbase + 4];
        float hv[8] = {h0.x,h0.y,h0.z,h0.w,h1.x,h1.y,h1.z,h1.w};
        float zv[8] = {z0.x,z0.y,z0.z,z0.w,z1.x,z1.y,z1.z,z1.w};
        float o[8];
#pragma unroll
        for (int j=0;j<8;++j) {
          float uu = tanhf(acc[i][j] + bb[j]);
          o[j] = hv[j] + dtv*(1.f - zv[j])*(uu - hv[j]);
        }
        *(float4*)&hio[(size_t)r*128 + cbase] = make_float4(o[0],o[1],o[2],o[3]);
        *(float4*)&hio[(size_t)r*128 + cbase + 4] = make_float4(o[4],o[5],o[6],o[7]);
      }
    }
  }
}

// ---------- row l2norm ----------
__global__ __launch_bounds__(128) void k_l2rows(const float* __restrict__ in, float* __restrict__ out) {
  int n = blockIdx.x, d = threadIdx.x;
  float v = in[(size_t)n*DD + d];
  __shared__ float red2[2];
  float ss = v*v;
  for (int off=32; off; off>>=1) ss += __shfl_down(ss, off);
  if ((d & 63)==0) red2[d>>6] = ss;
  __syncthreads();
  float inv = 1.f/fmaxf(sqrtf(red2[0]+red2[1]), 1e-12f);
  out[(size_t)n*DD + d] = v*inv;
}

// ---------- attention readout + W_sr + l2norm -> sr (B x D) ----------
__global__ __launch_bounds__(128) void k_attn(const float* __restrict__ fb, const float* __restrict__ U,
                                              const float* __restrict__ lv, const float* __restrict__ We,
                                              const float* __restrict__ W_sr, float* __restrict__ sr) {
  int b = blockIdx.x, d = threadIdx.x;
  __shared__ float sc[NPG];
  __shared__ float lastv[DD], srg[DD];
  __shared__ float red2[2];
  const float* Ub  = U  + (size_t)b*NPG*DD;
  const float* lvb = lv + (size_t)b*DD;
  if (d < 64) {
    for (int i=0;i<NPG;++i) {
      float e = We[d]   * sigmoidf_(Ub[i*DD + d]      + lvb[d]) +
                We[d+64]* sigmoidf_(Ub[i*DD + 64 + d] + lvb[d+64]);
      for (int off=32; off; off>>=1) e += __shfl_down(e, off);
      if (d==0) sc[i] = e;
    }
  }
  __syncthreads();
  if (d < 64) {
    float v = (d < NPG) ? sc[d] : -1e30f;
    float m = v;
    for (int off=1; off<64; off<<=1) m = fmaxf(m, __shfl_xor(m, off));
    float ex = (d < NPG) ? expf(v - m) : 0.f;
    float s = ex;
    for (int off=1; off<64; off<<=1) s += __shfl_xor(s, off);
    if (d < NPG) sc[d] = ex/s;
  }
  __syncthreads();
  const float* fbb = fb + (size_t)b*NPG*DD;
  float lastd = fbb[(NPG-1)*DD + d];
  float sg = 0.f;
  for (int i=0;i<NPG;++i) sg += fbb[i*DD + d]*sc[i];
  lastv[d] = lastd; srg[d] = sg;
  __syncthreads();
  float acc = 0.f;
  for (int k=0;k<DD;++k) acc += lastv[k]*W_sr[k*DD + d];
  for (int k=0;k<DD;++k) acc += srg[k]*W_sr[(DD+k)*DD + d];
  float ss = acc*acc;
  for (int off=32; off; off>>=1) ss += __shfl_down(ss, off);
  if ((d & 63)==0) red2[d>>6] = ss;
  __syncthreads();
  float inv = 1.f/fmaxf(sqrtf(red2[0]+red2[1]), 1e-12f);
  sr[(size_t)b*DD + d] = acc*inv;
}

// ---------- logits GEMM with fused scale + partial (max,sumexp) ----------
__global__ __launch_bounds__(256) void k_logits128(const float* __restrict__ srv, const float* __restrict__ emb,
                                                   const float* __restrict__ t_inv, float* __restrict__ out,
                                                   float* __restrict__ pmax, float* __restrict__ psum) {
  __shared__ float As[16][132];
  __shared__ float Bs[16][132];
  const int row0 = blockIdx.y*128, col0 = blockIdx.x*128;
  const int tid = threadIdx.x;
  const int tx = tid & 15, ty = tid >> 4;
  float acc[8][8] = {};
  for (int k0 = 0; k0 < 128; k0 += 16) {
#pragma unroll
    for (int i = 0; i < 2; ++i) {
      int idx = tid + 256*i;
      int m = idx >> 2, kq = idx & 3;
      float4 v = *(const float4*)&srv[(size_t)(row0+m)*DD + k0 + kq*4];
      As[kq*4+0][m] = v.x; As[kq*4+1][m] = v.y; As[kq*4+2][m] = v.z; As[kq*4+3][m] = v.w;
    }
#pragma unroll
    for (int i = 0; i < 2; ++i) {
      int idx = tid + 256*i;
      int j = idx >> 2, kq = idx & 3;
      int c = col0 + j;
      float4 v = make_float4(0.f,0.f,0.f,0.f);
      if (c < VV) v = *(const float4*)&emb[(size_t)c*DD + k0 + kq*4];
      Bs[kq*4+0][j] = v.x; Bs[kq*4+1][j] = v.y; Bs[kq*4+2][j] = v.z; Bs[kq*4+3][j] = v.w;
    }
    __syncthreads();
#pragma unroll
    for (int kk = 0; kk < 16; ++kk) {
      float4 a0 = *(const float4*)&As[kk][ty*8];
      float4 a1 = *(const float4*)&As[kk][ty*8+4];
      float4 b0 = *(const float4*)&Bs[kk][tx*8];
      float4 b1 = *(const float4*)&Bs[kk][tx*8+4];
      float av[8] = {a0.x,a0.y,a0.z,a0.w,a1.x,a1.y,a1.z,a1.w};
      float bv[8] = {b0.x,b0.y,b0.z,b0.w,b1.x,b1.y,b1.z,b1.w};
#pragma unroll
      for (int i=0;i<8;++i)
#pragma unroll
        for (int j=0;j<8;++j) acc[i][j] += av[i]*bv[j];
    }
    __syncthreads();
  }
  const int cbase = col0 + tx*8;
  float tin[8];
#pragma unroll
  for (int j=0;j<8;++j) tin[j] = (cbase+j < VV) ? FSCALE*t_inv[cbase+j] : 0.f;
  const bool full = (cbase + 7) < VV;
#pragma unroll
  for (int i=0;i<8;++i) {
    int r = row0 + ty*8 + i;
    float m = -1e30f;
#pragma unroll
    for (int j=0;j<8;++j) {
      if (cbase+j < VV) m = fmaxf(m, acc[i][j]*tin[j]);
    }
    float s = 0.f;
    float o[8];
#pragma unroll
    for (int j=0;j<8;++j) {
      float v = acc[i][j]*tin[j];
      o[j] = v;
      if (cbase+j < VV) s += expf(v - m);
    }
    if (full) {
      *(float4*)&out[(size_t)r*VV + cbase] = make_float4(o[0],o[1],o[2],o[3]);
      *(float4*)&out[(size_t)r*VV + cbase + 4] = make_float4(o[4],o[5],o[6],o[7]);
    } else {
#pragma unroll
      for (int j=0;j<8;++j) if (cbase+j < VV) out[(size_t)r*VV + cbase + j] = o[j];
    }
    // combine across the 16 tx lanes (same ty)
#pragma unroll
    for (int off=8; off; off>>=1) {
      float m2 = __shfl_xor(m, off);
      float s2 = __shfl_xor(s, off);
      float M = fmaxf(m, m2);
      s = s*expf(m - M) + s2*expf(m2 - M);
      m = M;
    }
    if (tx == 0) {
      pmax[(size_t)r*NCB + blockIdx.x] = m;
      psum[(size_t)r*NCB + blockIdx.x] = s;
    }
  }
}

__global__ __launch_bounds__(256) void k_lse(const float* __restrict__ pmax, const float* __restrict__ psum,
                                             float* __restrict__ lse) {
  int r = blockIdx.x, tid = threadIdx.x;
  float m = -1e30f, s = 0.f;
  for (int cb = tid; cb < NCB; cb += 256) {
    float m2 = pmax[(size_t)r*NCB + cb], s2 = psum[(size_t)r*NCB + cb];
    float M = fmaxf(m, m2);
    s = s*expf(m - M) + s2*expf(m2 - M);
    m = M;
  }
  __shared__ float ms[256], ssh[256];
  ms[tid] = m; ssh[tid] = s; __syncthreads();
  for (int st=128; st; st>>=1) {
    if (tid < st) {
      float m2 = ms[tid+st], s2 = ssh[tid+st];
      float M = fmaxf(ms[tid], m2);
      ssh[tid] = ssh[tid]*expf(ms[tid]-M) + s2*expf(m2-M);
      ms[tid] = M;
    }
    __syncthreads();
  }
  if (tid==0) lse[r] = ms[0] + logf(ssh[0]);
}

__global__ __launch_bounds__(256) void k_sub(float* __restrict__ out, const float* __restrict__ lse) {
  int idx = blockIdx.x*256 + threadIdx.x;
  int base = idx*4;
  if (base >= BB*VV) return;
  float l = lse[base / VV];
  float4* p = (float4*)(out + base);
  float4 v = *p;
  v.x -= l; v.y -= l; v.z -= l; v.w -= l;
  *p = v;
}

extern "C" void kernel_launch(void* const* d_in, const int* in_sizes, int n_in,
                              void* d_out, int out_size, void* d_ws, size_t ws_size,
                              hipStream_t stream) {
  (void)in_sizes; (void)n_in; (void)out_size; (void)ws_size;
  const int*   iid    = (const int*)  d_in[0];
  const int*   src    = (const int*)  d_in[1];
  const int*   dst    = (const int*)  d_in[2];
  const float* edge_w = (const float*)d_in[3];
  const float* edge_t = (const float*)d_in[4];
  const float* node_t = (const float*)d_in[5];
  const float* emb    = (const float*)d_in[6];
  const float* W1     = (const float*)d_in[7];
  const float* W2     = (const float*)d_in[8];
  const float* gw_ih  = (const float*)d_in[9];
  const float* gw_hh  = (const float*)d_in[10];
  const float* gb_ih  = (const float*)d_in[11];
  const float* gb_hh  = (const float*)d_in[12];
  const float* Wxr = (const float*)d_in[13]; const float* bxr = (const float*)d_in[14];
  const float* Wxz = (const float*)d_in[15]; const float* bxz = (const float*)d_in[16];
  const float* Wxh = (const float*)d_in[17]; const float* bxh = (const float*)d_in[18];
  const float* Whr = (const float*)d_in[19]; const float* bhr = (const float*)d_in[20];
  const float* Whz = (const float*)d_in[21]; const float* bhz = (const float*)d_in[22];
  const float* Whh = (const float*)d_in[23]; const float* bhh = (const float*)d_in[24];
  const float* Wu  = (const float*)d_in[25];
  const float* Wv  = (const float*)d_in[26]; const float* bv  = (const float*)d_in[27];
  const float* We  = (const float*)d_in[28];
  const float* W_sr= (const float*)d_in[29];

  float* ws  = (float*)d_ws;
  float* out = (float*)d_out;

  // workspace (floats) -- total ~1.44M floats (5.8 MB)
  float* t_inv = ws;                  // 100000
  float* dis   = t_inv + 100000;      // 25600
  float* emf   = dis + 25600;         // 30720
  float* M12   = emf + 30720;         // 256*384
  float* gihT  = M12 + 98304;         // 256*384
  float* ghhT  = gihT + 98304;        // 128*384
  float* Wrz   = ghhT + 49152;        // 256*256
  float* Wu2   = Wrz + 65536;         // 256*128
  float* brz   = Wu2 + 32768;         // 256
  float* bu    = brz + 256;           // 128
  float* lv    = bu + 128;            // 512*128
  float* srv   = lv + 65536;          // 512*128
  float* dtp   = srv + 65536;         // 4
  float* lse   = dtp + 4;             // 512
  float* pmax  = lse + 512;           // 512*782
  float* psum  = pmax + 400384;       // 512*782

  // d_out as scratch until the final logits pass (51.2M floats)
  float* AB  = out;                       // NN*256
  float* Crz = out + (size_t)6553600;     // NN*256
  float* x   = out + (size_t)13107200;    // NDTOT
  float* h   = out + (size_t)16384000;    // NDTOT
  float* gi  = out + (size_t)19660800;    // NN*384
  float* gh  = out + (size_t)29491200;    // NN*384
  float* U   = out + (size_t)19660800;    // NDTOT (reuses gi region after GRU)

  // ---- prep ----
  k_embnorm<<<VV/4, 256, 0, stream>>>(emb, t_inv);
  k_gather<<<NDTOT/256, 256, 0, stream>>>(iid, emb, t_inv, x);
  k_dt<<<1, 256, 0, stream>>>(edge_t, dtp);
  k_transpose<<<384, 256, 0, stream>>>(gw_ih, gihT, 256);
  k_transpose<<<384, 128, 0, stream>>>(gw_hh, ghhT, 128);
  k_build_wrz<<<256, 256, 0, stream>>>(Wxr, Wxz, Whr, Whz, Wrz);
  k_build_wu<<<256, 128, 0, stream>>>(Wxh, Whh, Wu2);
  k_build_bias<<<1, 384, 0, stream>>>(bxr, bhr, bxz, bhz, bxh, bhh, brz, bu);
  // M12 rows 0-127 = W1 @ gihT[0:128], rows 128-255 = W2 @ gihT[128:256]
  gemm128<<<dim3(3,1), 256, 0, stream>>>(W1, 128, gihT, 384, nullptr, M12, 384, 128, 0,
                                         nullptr, nullptr, nullptr, nullptr, nullptr, 0);
  gemm128<<<dim3(3,1), 256, 0, stream>>>(W2, 128, gihT + (size_t)128*384, 384, nullptr,
                                         M12 + (size_t)128*384, 384, 128, 0,
                                         nullptr, nullptr, nullptr, nullptr, nullptr, 0);

  // ---- stage C: per-group neighbor means -> AB ----
  k_grp_mean1<<<BB, 128, 0, stream>>>(src, dst, edge_w, x, AB);
  k_grp_mean2<<<BB, 128, 0, stream>>>(src, dst, edge_w, x, AB);

  // ---- GRU ----
  gemm128<<<dim3(3,200), 256, 0, stream>>>(AB, 256, M12, 384, gb_ih, gi, 384, 256, 0,
                                           nullptr, nullptr, nullptr, nullptr, nullptr, 0);
  gemm128<<<dim3(3,200), 256, 0, stream>>>(x, 128, ghhT, 384, gb_hh, gh, 384, 128, 0,
                                           nullptr, nullptr, nullptr, nullptr, nullptr, 0);
  k_gru<<<NN, 128, 0, stream>>>(gi, gh, x, h);

  // ---- ODE: 4 Euler steps, 2 GEMMs each ----
  for (int k = 0; k < NSPLITS; ++k) {
    k_ode_agg1x<<<BB, 128, 0, stream>>>(src, dst, edge_t, node_t, dtp, k, x, AB, dis, emf);
    k_ode_agg1h<<<BB, 128, 0, stream>>>(src, dst, emf, dis, h, AB);
    gemm128<<<dim3(2,200), 256, 0, stream>>>(AB, 256, Wrz, 256, brz, Crz, 256, 256, 2,
                                             h, nullptr, nullptr, nullptr, nullptr, 0);
    k_ode_agg2<<<BB, 128, 0, stream>>>(src, dst, emf, dis, Crz, AB);
    gemm128<<<dim3(1,200), 256, 0, stream>>>(AB, 256, Wu2, 128, bu, h, 128, 256, 3,
                                             nullptr, h, Crz, node_t, dtp, k);
  }

  // ---- attention readout ----
  k_l2rows<<<NN, 128, 0, stream>>>(h, x);   // fb into x
  gemm128<<<dim3(1,200), 256, 0, stream>>>(x, 128, Wu, 128, nullptr, U, 128, 128, 0,
                                           nullptr, nullptr, nullptr, nullptr, nullptr, 0);
  gemm128<<<dim3(1,4), 256, 0, stream>>>(x + (size_t)(NPG-1)*DD, NPG*DD, Wv, 128, bv, lv, 128, 128, 0,
                                         nullptr, nullptr, nullptr, nullptr, nullptr, 0);
  k_attn<<<BB, 128, 0, stream>>>(x, U, lv, We, W_sr, srv);

  // ---- logits + log_softmax ----
  k_logits128<<<dim3(NCB,4), 256, 0, stream>>>(srv, emb, t_inv, out, pmax, psum);
  k_lse<<<BB, 256, 0, stream>>>(pmax, psum, lse);
  k_sub<<<(BB*VV/4)/256, 256, 0, stream>>>(out, lse);
}

// Round 3
// 939.032 us; speedup vs baseline: 2.2160x; 1.5297x over previous
//
#include <hip/hip_runtime.h>

#define BB 512
#define NPG 50
#define EPG 60
#define DD 128
#define VV 100000
#define VPAD 100032
#define NSPLITS 4
#define FSCALE 12.0f
#define NN (BB*NPG)        // 25600
#define EE (BB*EPG)        // 30720
#define NDTOT (NN*DD)      // 3276800
#define NCB (VPAD/64)      // 1563

typedef __attribute__((ext_vector_type(8))) short bfx8;
typedef __attribute__((ext_vector_type(4))) float f32x4;

__device__ __forceinline__ float sigmoidf_(float x){ return 1.f/(1.f+expf(-x)); }
__device__ __forceinline__ short f2bf(float f){
  union { float f; unsigned u; } v; v.f = f;
  unsigned r = v.u + 0x7FFF + ((v.u >> 16) & 1);
  return (short)(r >> 16);
}

// ---------- embn = l2norm(emb) in bf16, padded to VPAD rows ----------
__global__ __launch_bounds__(256) void k_embn(const float* __restrict__ emb, short* __restrict__ embn) {
  int row = blockIdx.x*4 + (threadIdx.x >> 6);
  int lane = threadIdx.x & 63;
  if (row >= VPAD) return;
  if (row >= VV) { embn[(size_t)row*DD+lane]=0; embn[(size_t)row*DD+64+lane]=0; return; }
  const float* r = emb + (size_t)row*DD;
  float a = r[lane], b = r[lane+64];
  float s = a*a + b*b;
  for (int off=32; off; off>>=1) s += __shfl_down(s, off);
  s = __shfl(s, 0);
  float inv = 1.0f/fmaxf(sqrtf(s), 1e-12f);
  embn[(size_t)row*DD+lane]    = f2bf(a*inv);
  embn[(size_t)row*DD+64+lane] = f2bf(b*inv);
}

// ---------- feat = l2norm(emb[iid]) -> x fp32 + xb bf16 ----------
__global__ __launch_bounds__(128) void k_gather(const int* __restrict__ iid, const float* __restrict__ emb,
                                                float* __restrict__ x, short* __restrict__ xb) {
  int n = blockIdx.x, d = threadIdx.x;
  int v = iid[n];
  float e = emb[(size_t)v*DD + d];
  __shared__ float red2[2];
  float ss = e*e;
  for (int off=32; off; off>>=1) ss += __shfl_down(ss, off);
  if ((d & 63)==0) red2[d>>6] = ss;
  __syncthreads();
  float inv = 1.f/fmaxf(sqrtf(red2[0]+red2[1]), 1e-12f);
  float f = e*inv;
  x[(size_t)n*DD + d] = f;
  xb[(size_t)n*DD + d] = f2bf(f);
}

// ---------- dt = max(edge_t)/SPLITS ----------
__global__ __launch_bounds__(256) void k_dt(const float* __restrict__ edge_t, float* __restrict__ dtp) {
  __shared__ float red[256];
  float m = -1e30f;
  for (int e = threadIdx.x; e < EE; e += 256) m = fmaxf(m, edge_t[e]);
  red[threadIdx.x] = m; __syncthreads();
  for (int s=128; s; s>>=1){ if ((int)threadIdx.x < s) red[threadIdx.x] = fmaxf(red[threadIdx.x], red[threadIdx.x+s]); __syncthreads(); }
  if (threadIdx.x==0) dtp[0] = red[0] / (float)NSPLITS;
}

// ---------- weight prep (bf16, [N][K] transposed layouts) ----------
__global__ void k_m12t(const float* __restrict__ W1, const float* __restrict__ W2,
                       const float* __restrict__ gw_ih, short* __restrict__ M12t) {
  int c = blockIdx.x, k = threadIdx.x;             // c<384, k<256
  const float* Wrow = (k < 128) ? (W1 + (size_t)k*128) : (W2 + (size_t)(k-128)*128);
  const float* grow = gw_ih + (size_t)c*256 + ((k < 128) ? 0 : 128);
  float s = 0.f;
  for (int j = 0; j < 128; ++j) s += Wrow[j]*grow[j];
  M12t[(size_t)c*256 + k] = f2bf(s);
}
__global__ void k_bfcopy(const float* __restrict__ src, short* __restrict__ dst) {
  size_t i = (size_t)blockIdx.x*blockDim.x + threadIdx.x;
  dst[i] = f2bf(src[i]);
}
__global__ void k_wrzt(const float* __restrict__ Wxr, const float* __restrict__ Wxz,
                       const float* __restrict__ Whr, const float* __restrict__ Whz,
                       short* __restrict__ Wrzt) {
  int c = blockIdx.x, k = threadIdx.x;             // 256 x 256
  float v;
  if (k < 128) v = (c < 128) ? Wxr[k*128+c] : Wxz[k*128+(c-128)];
  else         v = (c < 128) ? Whr[(k-128)*128+c] : Whz[(k-128)*128+(c-128)];
  Wrzt[(size_t)c*256 + k] = f2bf(v);
}
__global__ void k_wu2t(const float* __restrict__ Wxh, const float* __restrict__ Whh, short* __restrict__ Wu2t) {
  int c = blockIdx.x, k = threadIdx.x;             // 128 x 256
  float v = (k < 128) ? Wxh[k*128+c] : Whh[(k-128)*128+c];
  Wu2t[(size_t)c*256 + k] = f2bf(v);
}
__global__ void k_wt128(const float* __restrict__ W, short* __restrict__ Wt) {
  int c = blockIdx.x, k = threadIdx.x;             // 128 x 128
  Wt[(size_t)c*128 + k] = f2bf(W[(size_t)k*128 + c]);
}
__global__ void k_build_bias(const float* __restrict__ bxr, const float* __restrict__ bhr,
                             const float* __restrict__ bxz, const float* __restrict__ bhz,
                             const float* __restrict__ bxh, const float* __restrict__ bhh,
                             float* __restrict__ brz, float* __restrict__ bu) {
  int t = threadIdx.x;
  if (t < 128) brz[t] = bxr[t] + bhr[t];
  else if (t < 256) brz[t] = bxz[t-128] + bhz[t-128];
  else bu[t-256] = bxh[t-256] + bhh[t-256];
}

// ---------- per-group stage-C means -> ABb bf16 ----------
__global__ __launch_bounds__(128) void k_grp_mean1(const int* __restrict__ src, const int* __restrict__ dst,
                                                   const float* __restrict__ ew, const float* __restrict__ feat,
                                                   short* __restrict__ ABb) {
  __shared__ float fl[NPG*128];
  __shared__ float n1[NPG*128];
  __shared__ int sl[EPG], tl[EPG];
  __shared__ float wl[EPG];
  __shared__ float d1[NPG];
  int b = blockIdx.x, d = threadIdx.x;
  int nb = b*NPG, eb = b*EPG;
  for (int i = d; i < NPG*32; i += 128) {
    ((float4*)fl)[i] = ((const float4*)(feat + (size_t)nb*128))[i];
    ((float4*)n1)[i] = make_float4(0.f,0.f,0.f,0.f);
  }
  if (d < EPG) { sl[d] = src[eb+d]-nb; tl[d] = dst[eb+d]-nb; wl[d] = ew[eb+d]; }
  __syncthreads();
  for (int e = 0; e < EPG; ++e)
    n1[tl[e]*128+d] += fl[sl[e]*128+d]*wl[e];
  if (d < NPG) {
    float den = 0.f;
    for (int e = 0; e < EPG; ++e) den += (tl[e]==d) ? wl[e] : 0.f;
    d1[d] = (den == 0.f) ? 1.f : den;
  }
  __syncthreads();
  for (int n = 0; n < NPG; ++n)
    ABb[(size_t)(nb+n)*256 + d] = f2bf(n1[n*128+d]/d1[n]);
}
__global__ __launch_bounds__(128) void k_grp_mean2(const int* __restrict__ src, const int* __restrict__ dst,
                                                   const float* __restrict__ ew, const float* __restrict__ feat,
                                                   short* __restrict__ ABb) {
  __shared__ float fl[NPG*128];
  __shared__ float n2[NPG*128];
  __shared__ int sl[EPG], tl[EPG];
  __shared__ float wl[EPG];
  __shared__ float d2[NPG];
  int b = blockIdx.x, d = threadIdx.x;
  int nb = b*NPG, eb = b*EPG;
  for (int i = d; i < NPG*32; i += 128) {
    ((float4*)fl)[i] = ((const float4*)(feat + (size_t)nb*128))[i];
    ((float4*)n2)[i] = make_float4(0.f,0.f,0.f,0.f);
  }
  if (d < EPG) { sl[d] = src[eb+d]-nb; tl[d] = dst[eb+d]-nb; wl[d] = ew[eb+d]; }
  __syncthreads();
  for (int e = 0; e < EPG; ++e)
    n2[sl[e]*128+d] += fl[tl[e]*128+d]*wl[e];
  if (d < NPG) {
    float den = 0.f;
    for (int e = 0; e < EPG; ++e) den += (sl[e]==d) ? wl[e] : 0.f;
    d2[d] = (den == 0.f) ? 1.f : den;
  }
  __syncthreads();
  for (int n = 0; n < NPG; ++n)
    ABb[(size_t)(nb+n)*256 + 128 + d] = f2bf(n2[n*128+d]/d2[n]);
}

// ---------- GRU + l2norm ----------
__global__ __launch_bounds__(128) void k_gru(const float* __restrict__ gi, const float* __restrict__ gh,
                                             float* __restrict__ x, float* __restrict__ h) {
  int n = blockIdx.x, d = threadIdx.x;
  const float* gin = gi + (size_t)n*384;
  const float* ghn = gh + (size_t)n*384;
  float ir = gin[d], iz = gin[128+d], ig = gin[256+d];
  float hr = ghn[d], hz = ghn[128+d], hg = ghn[256+d];
  float f0 = x[(size_t)n*DD + d];
  float r = sigmoidf_(ir + hr);
  float z = sigmoidf_(iz + hz);
  float g = tanhf(ig + r*hg);
  float f = (1.f - z)*g + z*f0;
  __shared__ float red2[2];
  float ss = f*f;
  for (int off=32; off; off>>=1) ss += __shfl_down(ss, off);
  if ((d & 63)==0) red2[d>>6] = ss;
  __syncthreads();
  float inv = 1.f/fmaxf(sqrtf(red2[0]+red2[1]), 1e-12f);
  float out = f*inv;
  x[(size_t)n*DD + d] = out;
  h[(size_t)n*DD + d] = out;
}

// ---------- ODE per-group aggregations ----------
__global__ __launch_bounds__(128) void k_ode_agg1x(const int* __restrict__ src, const int* __restrict__ dst,
                                                   const float* __restrict__ edge_t, const float* __restrict__ node_t,
                                                   const float* __restrict__ dtp, int kstep,
                                                   const float* __restrict__ x, short* __restrict__ ABb,
                                                   float* __restrict__ dis_ws, float* __restrict__ emf_ws) {
  __shared__ float xl[NPG*128];
  __shared__ float ax[NPG*128];
  __shared__ int sl[EPG], tl[EPG];
  __shared__ float actl[EPG];
  __shared__ float disl[NPG];
  __shared__ float ntl[NPG];
  int b = blockIdx.x, d = threadIdx.x;
  int nb = b*NPG, eb = b*EPG;
  float t = (float)kstep * dtp[0];
  if (d < EPG) { sl[d] = src[eb+d]-nb; tl[d] = dst[eb+d]-nb; }
  if (d < NPG) ntl[d] = node_t[nb+d];
  for (int i = d; i < NPG*32; i += 128) {
    ((float4*)xl)[i] = ((const float4*)(x + (size_t)nb*128))[i];
    ((float4*)ax)[i] = make_float4(0.f,0.f,0.f,0.f);
  }
  __syncthreads();
  if (d < EPG) {
    int s = sl[d], tt = tl[d];
    float a = (edge_t[eb+d] <= t && ntl[s] >= t && ntl[tt] >= t && s != tt) ? 1.f : 0.f;
    actl[d] = a;
    emf_ws[eb+d] = a;
  }
  __syncthreads();
  if (d < NPG) {
    float deg = 0.f;
    for (int e = 0; e < EPG; ++e) deg += actl[e]*((sl[e]==d ? 1.f:0.f)+(tl[e]==d ? 1.f:0.f));
    disl[d] = rsqrtf(fmaxf(deg, 1.f));
    dis_ws[nb+d] = disl[d];
  }
  __syncthreads();
  for (int e = 0; e < EPG; ++e) {
    if (actl[e] != 0.f) {
      int s = sl[e], tt = tl[e];
      ax[tt*128+d] += xl[s*128+d]*disl[s];
      ax[s*128+d]  += xl[tt*128+d]*disl[tt];
    }
  }
  __syncthreads();
  for (int n = 0; n < NPG; ++n)
    ABb[(size_t)(nb+n)*256 + d] = f2bf(ax[n*128+d]*disl[n]);
}

__global__ __launch_bounds__(128) void k_ode_agg1h(const int* __restrict__ src, const int* __restrict__ dst,
                                                   const float* __restrict__ emf_ws, const float* __restrict__ dis_ws,
                                                   const float* __restrict__ h, short* __restrict__ ABb) {
  __shared__ float hl[NPG*128];
  __shared__ float ah[NPG*128];
  __shared__ int sl[EPG], tl[EPG];
  __shared__ float actl[EPG];
  __shared__ float disl[NPG];
  int b = blockIdx.x, d = threadIdx.x;
  int nb = b*NPG, eb = b*EPG;
  if (d < EPG) { sl[d] = src[eb+d]-nb; tl[d] = dst[eb+d]-nb; actl[d] = emf_ws[eb+d]; }
  if (d < NPG) disl[d] = dis_ws[nb+d];
  for (int i = d; i < NPG*32; i += 128) {
    ((float4*)hl)[i] = ((const float4*)(h + (size_t)nb*128))[i];
    ((float4*)ah)[i] = make_float4(0.f,0.f,0.f,0.f);
  }
  __syncthreads();
  for (int e = 0; e < EPG; ++e) {
    if (actl[e] != 0.f) {
      int s = sl[e], tt = tl[e];
      ah[tt*128+d] += hl[s*128+d]*disl[s];
      ah[s*128+d]  += hl[tt*128+d]*disl[tt];
    }
  }
  __syncthreads();
  for (int n = 0; n < NPG; ++n)
    ABb[(size_t)(nb+n)*256 + 128 + d] = f2bf(ah[n*128+d]*disl[n]);
}

__global__ __launch_bounds__(128) void k_ode_agg2(const int* __restrict__ src, const int* __restrict__ dst,
                                                  const float* __restrict__ emf_ws, const float* __restrict__ dis_ws,
                                                  const float* __restrict__ rh, short* __restrict__ ABb) {
  __shared__ float rl[NPG*128];
  __shared__ float ar[NPG*128];
  __shared__ int sl[EPG], tl[EPG];
  __shared__ float actl[EPG];
  __shared__ float disl[NPG];
  int b = blockIdx.x, d = threadIdx.x;
  int nb = b*NPG, eb = b*EPG;
  if (d < EPG) { sl[d] = src[eb+d]-nb; tl[d] = dst[eb+d]-nb; actl[d] = emf_ws[eb+d]; }
  if (d < NPG) disl[d] = dis_ws[nb+d];
  for (int i = d; i < NPG*32; i += 128) {
    ((float4*)rl)[i] = ((const float4*)(rh + (size_t)nb*128))[i];
    ((float4*)ar)[i] = make_float4(0.f,0.f,0.f,0.f);
  }
  __syncthreads();
  for (int e = 0; e < EPG; ++e) {
    if (actl[e] != 0.f) {
      int s = sl[e], tt = tl[e];
      ar[tt*128+d] += rl[s*128+d]*disl[s];
      ar[s*128+d]  += rl[tt*128+d]*disl[tt];
    }
  }
  __syncthreads();
  for (int n = 0; n < NPG; ++n)
    ABb[(size_t)(nb+n)*256 + 128 + d] = f2bf(ar[n*128+d]*disl[n]);
}

// ---------- bf16 MFMA GEMM: 64x64 block tile, 4 waves, 16x16x32 ----------
// A [M][K] bf16 (lda), Bt [N][K] bf16 (ldbt). modes:
// 0: C = A@B + bias (fp32, ldc)
// 2: s=sigmoid(acc+brz[c]); c<128: rh[r][c]=s*h[r][c]; else zb[r][c-128]=s
// 3: uu=tanh(acc+bu[c]); if node_t[r]>=k*dt: h[r][c] += dt*(1-zb[r][c])*(uu-h[r][c])
// 4: logits: store out[r][c] (c<VV) + per-64col-block (max,sumexp) partials
__global__ __launch_bounds__(256) void gemm_mfma(
    const short* __restrict__ A, int lda,
    const short* __restrict__ Bt, int ldbt,
    const float* __restrict__ bias,
    float* __restrict__ C, int ldc,
    int K, int mode,
    float* __restrict__ rh, float* __restrict__ zb,
    float* __restrict__ hbuf,
    const float* __restrict__ node_t,
    const float* __restrict__ dtp, int kstep,
    float* __restrict__ outp, float* __restrict__ pmax, float* __restrict__ psum)
{
  __shared__ short As[64*40];
  __shared__ short Bs[64*40];
  const int tid = threadIdx.x;
  const int wave = tid >> 6, lane = tid & 63;
  const int wr = wave >> 1, wc = wave & 1;
  const int quad = lane >> 4, l16 = lane & 15;
  const int row0 = blockIdx.y*64, col0 = blockIdx.x*64;
  f32x4 acc[2][2] = {{{0.f,0.f,0.f,0.f},{0.f,0.f,0.f,0.f}},{{0.f,0.f,0.f,0.f},{0.f,0.f,0.f,0.f}}};
  const int sm = tid >> 2, skq = tid & 3;
  const short* Ap = A + (size_t)(row0+sm)*lda + skq*8;
  const short* Bp = Bt + (size_t)(col0+sm)*ldbt + skq*8;
  for (int k0 = 0; k0 < K; k0 += 32) {
    *(bfx8*)&As[sm*40 + skq*8] = *(const bfx8*)(Ap + k0);
    *(bfx8*)&Bs[sm*40 + skq*8] = *(const bfx8*)(Bp + k0);
    __syncthreads();
    bfx8 a0 = *(bfx8*)&As[(wr*32 + l16)*40 + quad*8];
    bfx8 a1 = *(bfx8*)&As[(wr*32 + 16 + l16)*40 + quad*8];
    bfx8 b0 = *(bfx8*)&Bs[(wc*32 + l16)*40 + quad*8];
    bfx8 b1 = *(bfx8*)&Bs[(wc*32 + 16 + l16)*40 + quad*8];
    acc[0][0] = __builtin_amdgcn_mfma_f32_16x16x32_bf16(a0, b0, acc[0][0], 0, 0, 0);
    acc[0][1] = __builtin_amdgcn_mfma_f32_16x16x32_bf16(a0, b1, acc[0][1], 0, 0, 0);
    acc[1][0] = __builtin_amdgcn_mfma_f32_16x16x32_bf16(a1, b0, acc[1][0], 0, 0, 0);
    acc[1][1] = __builtin_amdgcn_mfma_f32_16x16x32_bf16(a1, b1, acc[1][1], 0, 0, 0);
    __syncthreads();
  }

  if (mode == 0) {
#pragma unroll
    for (int i = 0; i < 2; ++i)
#pragma unroll
      for (int j = 0; j < 2; ++j) {
        int gc = col0 + wc*32 + j*16 + l16;
        float bb = bias ? bias[gc] : 0.f;
#pragma unroll
        for (int r = 0; r < 4; ++r) {
          int gr = row0 + wr*32 + i*16 + quad*4 + r;
          C[(size_t)gr*ldc + gc] = acc[i][j][r] + bb;
        }
      }
  } else if (mode == 2) {
#pragma unroll
    for (int i = 0; i < 2; ++i)
#pragma unroll
      for (int j = 0; j < 2; ++j) {
        int gc = col0 + wc*32 + j*16 + l16;
        float bb = bias[gc];
#pragma unroll
        for (int r = 0; r < 4; ++r) {
          int gr = row0 + wr*32 + i*16 + quad*4 + r;
          float s = sigmoidf_(acc[i][j][r] + bb);
          if (gc < 128) rh[(size_t)gr*128 + gc] = s * hbuf[(size_t)gr*128 + gc];
          else          zb[(size_t)gr*128 + gc - 128] = s;
        }
      }
  } else if (mode == 3) {
    float dtv = dtp[0];
    float tt = (float)kstep * dtv;
#pragma unroll
    for (int i = 0; i < 2; ++i)
#pragma unroll
      for (int j = 0; j < 2; ++j) {
        int gc = col0 + wc*32 + j*16 + l16;
        float bb = bias[gc];
#pragma unroll
        for (int r = 0; r < 4; ++r) {
          int gr = row0 + wr*32 + i*16 + quad*4 + r;
          if (node_t[gr] >= tt) {
            float hv = hbuf[(size_t)gr*128 + gc];
            float zv = zb[(size_t)gr*128 + gc];
            float uu = tanhf(acc[i][j][r] + bb);
            hbuf[(size_t)gr*128 + gc] = hv + dtv*(1.f - zv)*(uu - hv);
          }
        }
      }
  } else { // mode 4
    __shared__ float pm[64][2], ps[64][2];
#pragma unroll
    for (int i = 0; i < 2; ++i) {
#pragma unroll
      for (int r = 0; r < 4; ++r) {
        int rloc = wr*32 + i*16 + quad*4 + r;
        int gr = row0 + rloc;
        int c0 = col0 + wc*32 + l16;
        int c1 = c0 + 16;
        float v0 = acc[i][0][r], v1 = acc[i][1][r];
        if (c0 < VV) outp[(size_t)gr*VV + c0] = v0; else v0 = -1e30f;
        if (c1 < VV) outp[(size_t)gr*VV + c1] = v1; else v1 = -1e30f;
        float m = fmaxf(v0, v1);
        float s = 0.f;
        if (c0 < VV) s += expf(v0 - m);
        if (c1 < VV) s += expf(v1 - m);
#pragma unroll
        for (int off = 1; off < 16; off <<= 1) {
          float m2 = __shfl_xor(m, off);
          float s2 = __shfl_xor(s, off);
          float M = fmaxf(m, m2);
          s = s*expf(m - M) + s2*expf(m2 - M);
          m = M;
        }
        if (l16 == 0) { pm[rloc][wc] = m; ps[rloc][wc] = s; }
      }
    }
    __syncthreads();
    if (tid < 64) {
      float m0 = pm[tid][0], m1 = pm[tid][1];
      float s0 = ps[tid][0], s1 = ps[tid][1];
      float M = fmaxf(m0, m1);
      float S = s0*expf(m0 - M) + s1*expf(m1 - M);
      pmax[(size_t)(row0 + tid)*NCB + blockIdx.x] = M;
      psum[(size_t)(row0 + tid)*NCB + blockIdx.x] = S;
    }
  }
}

// ---------- row l2norm (h -> fb fp32 + fbb bf16) ----------
__global__ __launch_bounds__(128) void k_l2rows(const float* __restrict__ in, float* __restrict__ out,
                                                short* __restrict__ outb) {
  int n = blockIdx.x, d = threadIdx.x;
  float v = in[(size_t)n*DD + d];
  __shared__ float red2[2];
  float ss = v*v;
  for (int off=32; off; off>>=1) ss += __shfl_down(ss, off);
  if ((d & 63)==0) red2[d>>6] = ss;
  __syncthreads();
  float inv = 1.f/fmaxf(sqrtf(red2[0]+red2[1]), 1e-12f);
  float f = v*inv;
  out[(size_t)n*DD + d] = f;
  outb[(size_t)n*DD + d] = f2bf(f);
}

// ---------- attention readout + W_sr + l2norm -> srvb bf16 (pre-scaled) ----------
__global__ __launch_bounds__(128) void k_attn(const float* __restrict__ fb, const float* __restrict__ U,
                                              const float* __restrict__ lv, const float* __restrict__ We,
                                              const float* __restrict__ W_sr, short* __restrict__ srvb) {
  int b = blockIdx.x, d = threadIdx.x;
  __shared__ float sc[NPG];
  __shared__ float lastv[DD], srg[DD];
  __shared__ float red2[2];
  const float* Ub  = U  + (size_t)b*NPG*DD;
  const float* lvb = lv + (size_t)b*DD;
  if (d < 64) {
    for (int i=0;i<NPG;++i) {
      float e = We[d]   * sigmoidf_(Ub[i*DD + d]      + lvb[d]) +
                We[d+64]* sigmoidf_(Ub[i*DD + 64 + d] + lvb[d+64]);
      for (int off=32; off; off>>=1) e += __shfl_down(e, off);
      if (d==0) sc[i] = e;
    }
  }
  __syncthreads();
  if (d < 64) {
    float v = (d < NPG) ? sc[d] : -1e30f;
    float m = v;
    for (int off=1; off<64; off<<=1) m = fmaxf(m, __shfl_xor(m, off));
    float ex = (d < NPG) ? expf(v - m) : 0.f;
    float s = ex;
    for (int off=1; off<64; off<<=1) s += __shfl_xor(s, off);
    if (d < NPG) sc[d] = ex/s;
  }
  __syncthreads();
  const float* fbb = fb + (size_t)b*NPG*DD;
  float lastd = fbb[(NPG-1)*DD + d];
  float sg = 0.f;
  for (int i=0;i<NPG;++i) sg += fbb[i*DD + d]*sc[i];
  lastv[d] = lastd; srg[d] = sg;
  __syncthreads();
  float acc = 0.f;
  for (int k=0;k<DD;++k) acc += lastv[k]*W_sr[k*DD + d];
  for (int k=0;k<DD;++k) acc += srg[k]*W_sr[(DD+k)*DD + d];
  float ss = acc*acc;
  for (int off=32; off; off>>=1) ss += __shfl_down(ss, off);
  if ((d & 63)==0) red2[d>>6] = ss;
  __syncthreads();
  float inv = 1.f/fmaxf(sqrtf(red2[0]+red2[1]), 1e-12f);
  srvb[(size_t)b*DD + d] = f2bf(FSCALE*acc*inv);
}

__global__ __launch_bounds__(256) void k_lse(const float* __restrict__ pmax, const float* __restrict__ psum,
                                             float* __restrict__ lse) {
  int r = blockIdx.x, tid = threadIdx.x;
  float m = -1e30f, s = 0.f;
  for (int cb = tid; cb < NCB; cb += 256) {
    float m2 = pmax[(size_t)r*NCB + cb], s2 = psum[(size_t)r*NCB + cb];
    float M = fmaxf(m, m2);
    s = s*expf(m - M) + s2*expf(m2 - M);
    m = M;
  }
  __shared__ float ms[256], ssh[256];
  ms[tid] = m; ssh[tid] = s; __syncthreads();
  for (int st=128; st; st>>=1) {
    if (tid < st) {
      float m2 = ms[tid+st], s2 = ssh[tid+st];
      float M = fmaxf(ms[tid], m2);
      ssh[tid] = ssh[tid]*expf(ms[tid]-M) + s2*expf(m2-M);
      ms[tid] = M;
    }
    __syncthreads();
  }
  if (tid==0) lse[r] = ms[0] + logf(ssh[0]);
}

__global__ __launch_bounds__(256) void k_sub(float* __restrict__ out, const float* __restrict__ lse) {
  int idx = blockIdx.x*256 + threadIdx.x;
  int base = idx*4;
  if (base >= BB*VV) return;
  float l = lse[base / VV];
  float4* p = (float4*)(out + base);
  float4 v = *p;
  v.x -= l; v.y -= l; v.z -= l; v.w -= l;
  *p = v;
}

extern "C" void kernel_launch(void* const* d_in, const int* in_sizes, int n_in,
                              void* d_out, int out_size, void* d_ws, size_t ws_size,
                              hipStream_t stream) {
  (void)in_sizes; (void)n_in; (void)out_size; (void)ws_size;
  const int*   iid    = (const int*)  d_in[0];
  const int*   src    = (const int*)  d_in[1];
  const int*   dst    = (const int*)  d_in[2];
  const float* edge_w = (const float*)d_in[3];
  const float* edge_t = (const float*)d_in[4];
  const float* node_t = (const float*)d_in[5];
  const float* emb    = (const float*)d_in[6];
  const float* W1     = (const float*)d_in[7];
  const float* W2     = (const float*)d_in[8];
  const float* gw_ih  = (const float*)d_in[9];
  const float* gw_hh  = (const float*)d_in[10];
  const float* gb_ih  = (const float*)d_in[11];
  const float* gb_hh  = (const float*)d_in[12];
  const float* Wxr = (const float*)d_in[13]; const float* bxr = (const float*)d_in[14];
  const float* Wxz = (const float*)d_in[15]; const float* bxz = (const float*)d_in[16];
  const float* Wxh = (const float*)d_in[17]; const float* bxh = (const float*)d_in[18];
  const float* Whr = (const float*)d_in[19]; const float* bhr = (const float*)d_in[20];
  const float* Whz = (const float*)d_in[21]; const float* bhz = (const float*)d_in[22];
  const float* Whh = (const float*)d_in[23]; const float* bhh = (const float*)d_in[24];
  const float* Wu  = (const float*)d_in[25];
  const float* Wv  = (const float*)d_in[26]; const float* bv  = (const float*)d_in[27];
  const float* We  = (const float*)d_in[28];
  const float* W_sr= (const float*)d_in[29];

  float* ws  = (float*)d_ws;
  float* out = (float*)d_out;

  // ---- workspace layout (float units; shorts live in float-sized slots) ----
  short* embn = (short*)ws;                         // VPAD*128 shorts = 6,402,048 fl
  float* pmax = ws + 6402048;                       // 512*1563 = 800,256
  float* psum = pmax + 800256;                      // 800,256
  short* M12t = (short*)(psum + 800256);            // 384*256 sh = 49,152 fl
  short* gwhhb= (short*)(psum + 800256 + 49152);    // 384*128 sh = 24,576 fl
  short* Wrzt = (short*)(psum + 800256 + 73728);    // 256*256 sh = 32,768 fl
  short* Wu2t = (short*)(psum + 800256 + 106496);   // 128*256 sh = 16,384 fl
  short* Wut  = (short*)(psum + 800256 + 122880);   // 128*128 sh = 8,192 fl
  short* Wvt  = (short*)(psum + 800256 + 131072);   // 8,192 fl
  float* brz  = psum + 800256 + 139264;             // 256
  float* bu   = brz + 256;                          // 128
  float* lv   = bu + 128;                           // 65,536
  float* dis  = lv + 65536;                         // 25,600
  float* emf  = dis + 25600;                        // 30,720
  float* dtp  = emf + 30720;                        // 4
  float* lse  = dtp + 4;                            // 512

  // ---- d_out as scratch until the logits pass (51.2M floats) ----
  short* ABb = (short*)out;                         // 25600*256 sh (3.28M fl)
  float* x   = out + (size_t) 4*1024*1024;          // 3.28M
  float* h   = out + (size_t) 8*1024*1024;          // 3.28M
  float* rh  = out + (size_t)12*1024*1024;          // 3.28M
  float* zb  = out + (size_t)16*1024*1024;          // 3.28M
  float* gi  = out + (size_t)20*1024*1024;          // 9.83M
  float* gh  = out + (size_t)30*1024*1024;          // 9.83M
  float* U   = out + (size_t)20*1024*1024;          // reuse gi after GRU
  short* xb  = (short*)(out + (size_t)40*1024*1024);// 25600*128 sh (1.64M fl)
  short* fbb = (short*)(out + (size_t)42*1024*1024);// 1.64M fl

  // ---- prep ----
  k_embn<<<VPAD/4, 256, 0, stream>>>(emb, embn);
  k_gather<<<NN, 128, 0, stream>>>(iid, emb, x, xb);
  k_dt<<<1, 256, 0, stream>>>(edge_t, dtp);
  k_m12t<<<384, 256, 0, stream>>>(W1, W2, gw_ih, M12t);
  k_bfcopy<<<384, 128, 0, stream>>>(gw_hh, gwhhb);
  k_wrzt<<<256, 256, 0, stream>>>(Wxr, Wxz, Whr, Whz, Wrzt);
  k_wu2t<<<128, 256, 0, stream>>>(Wxh, Whh, Wu2t);
  k_wt128<<<128, 128, 0, stream>>>(Wu, Wut);
  k_wt128<<<128, 128, 0, stream>>>(Wv, Wvt);
  k_build_bias<<<1, 384, 0, stream>>>(bxr, bhr, bxz, bhz, bxh, bhh, brz, bu);

  // ---- stage C ----
  k_grp_mean1<<<BB, 128, 0, stream>>>(src, dst, edge_w, x, ABb);
  k_grp_mean2<<<BB, 128, 0, stream>>>(src, dst, edge_w, x, ABb);

  // ---- GRU ----
  gemm_mfma<<<dim3(6,400), 256, 0, stream>>>(ABb, 256, M12t, 256, gb_ih, gi, 384, 256, 0,
      nullptr, nullptr, nullptr, nullptr, nullptr, 0, nullptr, nullptr, nullptr);
  gemm_mfma<<<dim3(6,400), 256, 0, stream>>>(xb, 128, gwhhb, 128, gb_hh, gh, 384, 128, 0,
      nullptr, nullptr, nullptr, nullptr, nullptr, 0, nullptr, nullptr, nullptr);
  k_gru<<<NN, 128, 0, stream>>>(gi, gh, x, h);

  // ---- ODE ----
  for (int k = 0; k < NSPLITS; ++k) {
    k_ode_agg1x<<<BB, 128, 0, stream>>>(src, dst, edge_t, node_t, dtp, k, x, ABb, dis, emf);
    k_ode_agg1h<<<BB, 128, 0, stream>>>(src, dst, emf, dis, h, ABb);
    gemm_mfma<<<dim3(4,400), 256, 0, stream>>>(ABb, 256, Wrzt, 256, brz, nullptr, 0, 256, 2,
        rh, zb, h, nullptr, nullptr, 0, nullptr, nullptr, nullptr);
    k_ode_agg2<<<BB, 128, 0, stream>>>(src, dst, emf, dis, rh, ABb);
    gemm_mfma<<<dim3(2,400), 256, 0, stream>>>(ABb, 256, Wu2t, 256, bu, nullptr, 0, 256, 3,
        nullptr, zb, h, node_t, dtp, k, nullptr, nullptr, nullptr);
  }

  // ---- attention ----
  k_l2rows<<<NN, 128, 0, stream>>>(h, x, fbb);
  gemm_mfma<<<dim3(2,400), 256, 0, stream>>>(fbb, 128, Wut, 128, nullptr, U, 128, 128, 0,
      nullptr, nullptr, nullptr, nullptr, nullptr, 0, nullptr, nullptr, nullptr);
  gemm_mfma<<<dim3(2,8), 256, 0, stream>>>(fbb + (size_t)(NPG-1)*DD, NPG*DD, Wvt, 128, bv, lv, 128, 128, 0,
      nullptr, nullptr, nullptr, nullptr, nullptr, 0, nullptr, nullptr, nullptr);
  k_attn<<<BB, 128, 0, stream>>>(x, U, lv, We, W_sr, (short*)((float*)ws + 6402048 + 800256*2 + 139264 + 256 + 128 + 65536 + 25600 + 30720 + 4 + 512));

  short* srvb = (short*)((float*)ws + 6402048 + 800256*2 + 139264 + 256 + 128 + 65536 + 25600 + 30720 + 4 + 512);

  // ---- logits + log_softmax ----
  gemm_mfma<<<dim3(NCB,8), 256, 0, stream>>>(srvb, 128, embn, 128, nullptr, nullptr, 0, 128, 4,
      nullptr, nullptr, nullptr, nullptr, nullptr, 0, out, pmax, psum);
  k_lse<<<BB, 256, 0, stream>>>(pmax, psum, lse);
  k_sub<<<(BB*VV/4)/256, 256, 0, stream>>>(out, lse);
}